// Round 1
// baseline (67.885 us; speedup 1.0000x reference)
//
#include <hip/hip_runtime.h>
#include <hip/hip_bf16.h>
#include <float.h>

// GraphSAGE: masked-max agg + ReLU + concat + Linear(256->128).
// B=4, N=512, C=128, OUT=128.
//
// R11: latency-attack restructure of the 67us R10 kernel.
//  - 4 nodes/block (grid 512 = 2 blocks/CU target), wave w: node slot w&3,
//    row QUARTER w>>2 (128 adj entries = one float2 coalesced load,
//    ~13 nbrs -> ~2 gather rounds of 8 instead of ~4.5).
//  - __launch_bounds__(1024, 8): min 8 waves/EU => 2 x 16-wave blocks/CU
//    (100% wave occupancy) => compiler must fit <=64 VGPR. Lean code.
//  - Phase B K-split across ALL 16 waves: wave w -> n-tile w&7, K-half w>>3
//    (4 MFMA steps/wave instead of 8, halves the strided-W-load chain).
//    Partials combined via 2 KB LDS.
//  - No zero-fill of unused A-rows: MFMA output row m depends only on
//    A row m, so garbage in rows 4..15 never touches stored rows 0..3.
//  - Single dispatch, zero inter-block sync (R8/R9 lesson stands).

#define Bsz 4
#define Nn  512
#define Cc  128
#define OUTn 128
#define NNODES (Bsz * Nn)   // 2048
#define KK (2 * Cc)         // 256
#define ROWP 264            // LDS A-tile row stride (bf16): +8 -> 4-bank skew

typedef __bf16 bf16x8 __attribute__((ext_vector_type(8)));
typedef float  f32x4  __attribute__((ext_vector_type(4)));

static __device__ __forceinline__ unsigned short f2bf(float x) {
    __hip_bfloat16 h = __float2bfloat16(x);
    return *reinterpret_cast<unsigned short*>(&h);
}
static __device__ __forceinline__ __bf16 f2bf16(float x) {
    unsigned short u = f2bf(x);
    return *reinterpret_cast<__bf16*>(&u);
}

__global__ __launch_bounds__(1024, 8) void sage_fused(
    const float* __restrict__ adj,
    const float* __restrict__ feat,
    const float* __restrict__ W,      // fp32 [256][128]
    const float* __restrict__ bias,   // fp32 [128]
    float* __restrict__ out)          // fp32 [2048][128]
{
    const int bid = blockIdx.x;       // 0..511
    const int w = threadIdx.x >> 6;   // 0..15
    const int l = threadIdx.x & 63;

    const int slot = w & 3;           // node slot within the 4 rows
    const int q    = w >> 2;          // adjacency quarter [128q, 128q+128)
    const int node = bid * 4 + slot;
    const int b = node >> 9;
    const int i = node & (Nn - 1);

    __shared__ unsigned short nbr[16][128]; // per-wave compacted quarter-row
    __shared__ float2 pm[16][64];           // per-wave partial maxima
    __shared__ unsigned short sA[16][ROWP]; // bf16 A-tile (rows 4..15 unused)
    __shared__ f32x4 accbuf[8][16];         // K-half partial accumulators

    // ---- phase A: ballot-compact + 8-wide max-gather of a quarter row ----
    const float* adjrow = adj + (size_t)node * Nn;
    const float2* f2 = (const float2*)(feat + (size_t)b * Nn * Cc);

    int cnt = 0;
    {
        float2 a = *(const float2*)(adjrow + q * 128 + 2 * l);
        unsigned long long mk = __ballot(a.x > 0.0f);
        int pos = __popcll(mk & ((1ull << l) - 1ull));
        if (a.x > 0.0f) nbr[w][pos] = (unsigned short)(q * 128 + 2 * l);
        cnt = __popcll(mk);
        mk = __ballot(a.y > 0.0f);
        pos = __popcll(mk & ((1ull << l) - 1ull));
        if (a.y > 0.0f) nbr[w][cnt + pos] = (unsigned short)(q * 128 + 2 * l + 1);
        cnt += __popcll(mk);
    }
    // Pad to a multiple of 8 with a duplicate (max is idempotent).
    if (cnt > 0) {
        unsigned short p0 = nbr[w][0];
        int padded = (cnt + 7) & ~7;
        if (l < padded - cnt) nbr[w][cnt + l] = p0;
        cnt = padded;
    }
    // Same-wave DS write->read: lgkmcnt ordering guarantees visibility.

    float m0 = -FLT_MAX, m1 = -FLT_MAX;
    const uint4* nv = (const uint4*)&nbr[w][0];
    for (int k = 0; k < cnt; k += 8) {
        uint4 p = nv[k >> 3];                  // one b128 broadcast = 8 idx
        int j0 = p.x & 0xffff, j1 = p.x >> 16;
        int j2 = p.y & 0xffff, j3 = p.y >> 16;
        int j4 = p.z & 0xffff, j5 = p.z >> 16;
        int j6 = p.w & 0xffff, j7 = p.w >> 16;
        float2 v0 = f2[j0 * 64 + l];
        float2 v1 = f2[j1 * 64 + l];
        float2 v2 = f2[j2 * 64 + l];
        float2 v3 = f2[j3 * 64 + l];
        float2 v4 = f2[j4 * 64 + l];
        float2 v5 = f2[j5 * 64 + l];
        float2 v6 = f2[j6 * 64 + l];
        float2 v7 = f2[j7 * 64 + l];
        m0 = fmaxf(m0, fmaxf(fmaxf(fmaxf(v0.x, v1.x), fmaxf(v2.x, v3.x)),
                             fmaxf(fmaxf(v4.x, v5.x), fmaxf(v6.x, v7.x))));
        m1 = fmaxf(m1, fmaxf(fmaxf(fmaxf(v0.y, v1.y), fmaxf(v2.y, v3.y)),
                             fmaxf(fmaxf(v4.y, v5.y), fmaxf(v6.y, v7.y))));
    }
    pm[w][l] = make_float2(m0, m1);
    __syncthreads();

    // ---- combine quarters, relu, self row -> bf16 A-tile row (waves 0-3) --
    if (w < 4) {   // w<4 => q==0 => node/i above are this slot's node
        float2 a0 = pm[w][l],     a1 = pm[w + 4][l];
        float2 a2 = pm[w + 8][l], a3 = pm[w + 12][l];
        // relu(max) also maps no-neighbor (-FLT_MAX) to 0, matching the
        // reference (finfo.min is finite; its isfinite-guard never fires).
        float n0 = fmaxf(fmaxf(fmaxf(a0.x, a1.x), fmaxf(a2.x, a3.x)), 0.0f);
        float n1 = fmaxf(fmaxf(fmaxf(a0.y, a1.y), fmaxf(a2.y, a3.y)), 0.0f);
        float2 s = f2[i * 64 + l];

        ushort2* crow = (ushort2*)&sA[w][0];
        ushort2 sv; sv.x = f2bf(s.x); sv.y = f2bf(s.y);
        ushort2 nn; nn.x = f2bf(n0);  nn.y = f2bf(n1);
        crow[l]      = sv;   // self  ch [2l, 2l+1]
        crow[64 + l] = nn;   // neigh ch [128+2l, 128+2l+1]
    }
    __syncthreads();

    // ---- phase B: all 16 waves. wave w -> n-tile w&7, K-half w>>3 ----
    // A-frag: lane holds A[m=l&15][k=kbase+j] -> ds_read_b128 from sA.
    // B-frag: lane holds B[k=kbase+j][n=nt*16+(l&15)] from fp32 W + cvt.
    // C/D: col = lane&15, row = (lane>>4)*4 + reg   [measured m89/m91]
    const int nt = w & 7;
    const int kh = w >> 3;
    const int frow = l & 15;
    const int koff = (l >> 4) * 8;
    const float* wp = W + nt * 16 + frow;   // stride OUTn over k

    f32x4 acc = {0.f, 0.f, 0.f, 0.f};
    #pragma unroll
    for (int ks = 0; ks < 4; ++ks) {
        const int kbase = kh * 128 + ks * 32 + koff;
        bf16x8 af = *(const bf16x8*)&sA[frow][kbase];
        bf16x8 bfr;
        #pragma unroll
        for (int j = 0; j < 8; ++j) {
            bfr[j] = f2bf16(wp[(size_t)(kbase + j) * OUTn]);
        }
        acc = __builtin_amdgcn_mfma_f32_16x16x32_bf16(af, bfr, acc, 0, 0, 0);
    }

    // valid output rows are 0..3 -> only lanes l<16 (r0==0) carry them
    if (w >= 8 && l < 16) accbuf[nt][l] = acc;
    __syncthreads();

    if (w < 8 && l < 16) {
        f32x4 oth = accbuf[nt][l];
        const int col = l;                  // l&15 == l here
        const float bv = bias[nt * 16 + col];
        #pragma unroll
        for (int r = 0; r < 4; ++r) {
            out[(size_t)(bid * 4 + r) * OUTn + nt * 16 + col]
                = acc[r] + oth[r] + bv;
        }
    }
}

extern "C" void kernel_launch(void* const* d_in, const int* in_sizes, int n_in,
                              void* d_out, int out_size, void* d_ws, size_t ws_size,
                              hipStream_t stream) {
    const float* adj  = (const float*)d_in[0];
    const float* feat = (const float*)d_in[1];
    const float* W    = (const float*)d_in[2];
    const float* bias = (const float*)d_in[3];
    float* out = (float*)d_out;

    sage_fused<<<dim3(NNODES / 4), dim3(1024), 0, stream>>>(
        adj, feat, W, bias, out);
}